// Round 17
// baseline (391.687 us; speedup 1.0000x reference)
//
#include <hip/hip_runtime.h>

#define N_NODES 50000
#define N_EDGES 600000
#define N_GRAPHS 2048
#define EMB 128
#define TDIM 384
#define TS_LD 392               // padded LDS row stride (shorts): 2-way bank alias only
#define HN (N_NODES * EMB)
#define SCAN_NB ((N_NODES + 255) / 256)   // 196

// merged-prepass block ranges (384 threads/block)
#define PRE_ATOM_NB 16667       // ceil(50000/3) nodes, 3 per block (128 thr each)
#define PRE_HIST_NB 1563        // ceil(600000/384)
#define PRE_WCONV_NB 384        // one (layer,col) per block
#define PRE_GB_NB 131           // ceil(50000/384)

typedef __attribute__((ext_vector_type(8))) short bf16x8;
typedef __attribute__((ext_vector_type(4))) float f32x4;
#define MFMA_BF16(a, b, c) __builtin_amdgcn_mfma_f32_16x16x32_bf16(a, b, c, 0, 0, 0)

__device__ inline unsigned short f2bf(float f) {
  unsigned int u = __float_as_uint(f);
  u += 0x7fffu + ((u >> 16) & 1u);   // round to nearest even
  return (unsigned short)(u >> 16);
}
__device__ inline float bf2f(unsigned short b) {
  return __uint_as_float(((unsigned int)b) << 16);
}

// ---------------- merged prepass: atom-encoder | degree-hist | W-transpose | graph-bounds ----------
// All four are mutually independent; one launch instead of four.
__global__ __launch_bounds__(384) void k_pre(const int* __restrict__ x,
                                             const float* __restrict__ atom_emb,
                                             float* __restrict__ h,
                                             unsigned short* __restrict__ h_bf,
                                             const int* __restrict__ ei,
                                             int* __restrict__ deg,
                                             const float* __restrict__ W,
                                             unsigned short* __restrict__ wt,
                                             const int* __restrict__ batch,
                                             int* __restrict__ gs) {
  int blk = blockIdx.x;
  if (blk < PRE_ATOM_NB) {
    int n = blk * 3 + (threadIdx.x >> 7);
    int e = threadIdx.x & 127;
    if (n < N_NODES) {
      const int* xr = x + n * 9;
      float acc = 0.f;
#pragma unroll
      for (int c = 0; c < 9; ++c) acc += atom_emb[(c * 100 + xr[c]) * EMB + e];
      h[n * EMB + e] = acc;
      h_bf[n * EMB + e] = f2bf(acc);
    }
    return;
  }
  blk -= PRE_ATOM_NB;
  if (blk < PRE_HIST_NB) {
    int e = blk * 384 + threadIdx.x;
    if (e < N_EDGES) atomicAdd(&deg[ei[N_EDGES + e]], 1);
    return;
  }
  blk -= PRE_HIST_NB;
  if (blk < PRE_WCONV_NB) {
    int layer = blk >> 7, c = blk & 127, k = threadIdx.x;
    float v = W[(((layer * 3 + (k >> 7)) * 128) + (k & 127)) * 128 + c];
    wt[(size_t)blk * 384 + k] = f2bf(v);
    return;
  }
  blk -= PRE_WCONV_NB;
  {
    int i = blk * 384 + threadIdx.x;
    if (i < N_NODES) {
      int b = batch[i];
      int bp = (i == 0) ? -1 : batch[i - 1];
      for (int g = bp + 1; g <= b; ++g) gs[g] = i;
      if (i == N_NODES - 1) {
        for (int g = b + 1; g <= N_GRAPHS; ++g) gs[g] = N_NODES;
      }
    }
  }
}

// ---------------- CSR scan ----------------
__global__ __launch_bounds__(256) void k_scan_a(const int* __restrict__ deg,
                                                int* __restrict__ row_start,
                                                int* __restrict__ partials) {
  __shared__ int s[256];
  const int tid = threadIdx.x;
  const int i = blockIdx.x * 256 + tid;
  int v = (i < N_NODES) ? deg[i] : 0;
  s[tid] = v;
  __syncthreads();
  for (int off = 1; off < 256; off <<= 1) {
    int t = (tid >= off) ? s[tid - off] : 0;
    __syncthreads();
    s[tid] += t;
    __syncthreads();
  }
  if (i < N_NODES) row_start[i] = s[tid] - v;
  if (tid == 255) partials[blockIdx.x] = s[255];
}

__global__ __launch_bounds__(256) void k_scan_b(int* __restrict__ partials,
                                                int* __restrict__ row_start) {
  __shared__ int s[256];
  const int tid = threadIdx.x;
  int v = (tid < SCAN_NB) ? partials[tid] : 0;
  s[tid] = v;
  __syncthreads();
  for (int off = 1; off < 256; off <<= 1) {
    int t = (tid >= off) ? s[tid - off] : 0;
    __syncthreads();
    s[tid] += t;
    __syncthreads();
  }
  if (tid < SCAN_NB) partials[tid] = s[tid] - v;
  if (tid == 255) row_start[N_NODES] = s[255];
}

__global__ __launch_bounds__(256) void k_scan_c(int* __restrict__ row_start,
                                                const int* __restrict__ partials,
                                                int* __restrict__ cursor) {
  const int i = blockIdx.x * 256 + threadIdx.x;
  if (i < N_NODES) {
    int r = row_start[i] + partials[blockIdx.x];
    row_start[i] = r;
    cursor[i] = r;
  }
}

// Scatter edges into CSR order: one int2{src, packed_attr} per edge.
__global__ __launch_bounds__(256) void k_scatter(const int* __restrict__ ei,
                                                 const int* __restrict__ ea,
                                                 int* __restrict__ cursor,
                                                 int2* __restrict__ sorted_se) {
  int e = blockIdx.x * 256 + threadIdx.x;
  if (e >= N_EDGES) return;
  int src = ei[e], dst = ei[N_EDGES + e];
  int pos = atomicAdd(&cursor[dst], 1);
  int eap = ea[e * 3 + 0] | (ea[e * 3 + 1] << 3) | (ea[e * 3 + 2] << 6);
  sorted_se[pos] = int2{src, eap};
}

// ---------------- Edge aggregation (round-9 form + float4 pk-fma arithmetic) ----------------
// 2 nodes/wave (half-wave each, 32 lanes x ushort4), unroll-8, LDS combo.
// Inner FMA block written in float4 vector arithmetic so the compiler can emit
// v_pk_fma_f32 (2 FMAs/instr) — VALUBusy was 51%.
__global__ __launch_bounds__(256) void k_agg(const int2* __restrict__ sorted_se,
                                             const int* __restrict__ row_start,
                                             const float* __restrict__ bl,  // bond_emb[layer]: [3][8][3]
                                             const unsigned short* __restrict__ h_bf,
                                             unsigned short* __restrict__ t_bf) {
  __shared__ float4 combo[512];  // 8 KB
  for (int c = threadIdx.x; c < 512; c += 256) {
    int a0 = c & 7, a1 = (c >> 3) & 7, a2 = (c >> 6) & 7;
    combo[c] = float4{bl[a0 * 3 + 0] + bl[24 + a1 * 3 + 0] + bl[48 + a2 * 3 + 0],
                      bl[a0 * 3 + 1] + bl[24 + a1 * 3 + 1] + bl[48 + a2 * 3 + 1],
                      bl[a0 * 3 + 2] + bl[24 + a1 * 3 + 2] + bl[48 + a2 * 3 + 2], 0.f};
  }
  __syncthreads();
  const int node = blockIdx.x * 8 + (threadIdx.x >> 5);  // half-wave per node
  const int sub = threadIdx.x & 31;                      // cols sub*4..+3
  const int beg = row_start[node], end = row_start[node + 1];
  float4 a0 = {0.f, 0.f, 0.f, 0.f}, a1 = a0, a2 = a0;
  for (int e = beg; e < end; e += 8) {
    int2 se[8];
#pragma unroll
    for (int i = 0; i < 8; ++i) {
      int idx = e + i;
      se[i] = sorted_se[idx < end ? idx : end - 1];
    }
    ushort4 u[8];
#pragma unroll
    for (int i = 0; i < 8; ++i)
      u[i] = *(const ushort4*)(h_bf + (size_t)se[i].x * EMB + sub * 4);
#pragma unroll
    for (int i = 0; i < 8; ++i) {
      float4 w = (e + i < end) ? combo[se[i].y] : float4{0.f, 0.f, 0.f, 0.f};
      float4 vf = {bf2f(u[i].x), bf2f(u[i].y), bf2f(u[i].z), bf2f(u[i].w)};
      a0 += vf * w.x;
      a1 += vf * w.y;
      a2 += vf * w.z;
    }
  }
  size_t base = (size_t)node * TDIM + sub * 4;
  *(ushort4*)(t_bf + base)       = ushort4{f2bf(a0.x), f2bf(a0.y), f2bf(a0.z), f2bf(a0.w)};
  *(ushort4*)(t_bf + base + 128) = ushort4{f2bf(a1.x), f2bf(a1.y), f2bf(a1.z), f2bf(a1.w)};
  *(ushort4*)(t_bf + base + 256) = ushort4{f2bf(a2.x), f2bf(a2.y), f2bf(a2.z), f2bf(a2.w)};
}

// ---------------- MFMA GEMM: stage 32 t-rows into LDS (coalesced), then per-wave GEMM ----------------
// Block 512 thr = 8 waves; 32 nodes/block; grid 1563. Wave wv owns cols wv*16..+15:
// 12 resident B-frags, 2 row-tiles (A via ds_read_b128), 12 chained MFMAs each,
// inline bias+relu+residual epilogue. h ping-pong (gather safety).
// A-frag: A[m=lane&15][k=(lane>>4)*8+j]; B-frag: B[k][n=lane&15];
// C/D: col=lane&15, row=(lane>>4)*4+reg.
__global__ __launch_bounds__(512) void k_gemm(const unsigned short* __restrict__ t_bf,
                                              const unsigned short* __restrict__ wt,  // [128][384]
                                              const float* __restrict__ bl,  // [3][128]
                                              const float* __restrict__ h_in,
                                              float* __restrict__ h_out,
                                              unsigned short* __restrict__ h_out_bf,
                                              int do_relu, int write_bf) {
  __shared__ unsigned short ts[32 * TS_LD];   // 24.5 KB
  const int nb = blockIdx.x * 32;
  for (int i = threadIdx.x; i < 32 * 48; i += 512) {
    int r = i / 48, cc = i % 48;
    bf16x8 v = {};
    int row = nb + r;
    if (row < N_NODES) v = *(const bf16x8*)(t_bf + (size_t)row * TDIM + cc * 8);
    *(bf16x8*)(ts + r * TS_LD + cc * 8) = v;
  }
  __syncthreads();

  const int wv = threadIdx.x >> 6;
  const int lane = threadIdx.x & 63;
  const int m = lane & 15;
  const int kq = lane >> 4;
  const int c = wv * 16 + m;

  const unsigned short* pB = wt + (size_t)c * TDIM + kq * 8;
  bf16x8 B[12];
#pragma unroll
  for (int kc = 0; kc < 12; ++kc) B[kc] = *(const bf16x8*)(pB + kc * 32);

  const float bias = bl[c] + bl[128 + c] + bl[256 + c];

#pragma unroll
  for (int rt = 0; rt < 2; ++rt) {
    const unsigned short* pA = ts + (rt * 16 + m) * TS_LD + kq * 8;
    bf16x8 A[12];
#pragma unroll
    for (int kc = 0; kc < 12; ++kc) A[kc] = *(const bf16x8*)(pA + kc * 32);
    f32x4 acc = {0.f, 0.f, 0.f, 0.f};
#pragma unroll
    for (int kc = 0; kc < 12; ++kc) acc = MFMA_BF16(A[kc], B[kc], acc);
#pragma unroll
    for (int r = 0; r < 4; ++r) {
      int row = nb + rt * 16 + kq * 4 + r;
      if (row < N_NODES) {
        size_t idx = (size_t)row * EMB + c;
        float v = acc[r] + bias;
        if (do_relu) v = fmaxf(v, 0.f);
        float hn = h_in[idx] + v;
        h_out[idx] = hn;
        if (write_bf) h_out_bf[idx] = f2bf(hn);
      }
    }
  }
}

// ---------------- fused mean-pool + head: block g reduces its contiguous node range ----------------
__global__ __launch_bounds__(128) void k_head(const float* __restrict__ h,
                                              const int* __restrict__ gs,
                                              const float* __restrict__ fc1_w,
                                              const float* __restrict__ fc1_b,
                                              const float* __restrict__ fc2_w,
                                              const float* __restrict__ fc2_b,
                                              float* __restrict__ out) {
  __shared__ float hg[EMB];
  __shared__ float red[EMB];
  int g = blockIdx.x, e = threadIdx.x;
  int ns = gs[g], ne = gs[g + 1];
  float acc = 0.f;
  for (int n = ns; n < ne; ++n) acc += h[(size_t)n * EMB + e];
  float cnt = fmaxf((float)(ne - ns), 1.f);
  hg[e] = acc / cnt;
  __syncthreads();
  float a2 = fc1_b[e];
  for (int j = 0; j < EMB; ++j) a2 += hg[j] * fc1_w[j * EMB + e];
  red[e] = a2 * fc2_w[e];
  __syncthreads();
  for (int s = 64; s > 0; s >>= 1) {
    if (e < s) red[e] += red[e + s];
    __syncthreads();
  }
  if (e == 0) out[g] = red[0] + fc2_b[0];
}

extern "C" void kernel_launch(void* const* d_in, const int* in_sizes, int n_in,
                              void* d_out, int out_size, void* d_ws, size_t ws_size,
                              hipStream_t stream) {
  const int*   x        = (const int*)d_in[0];
  const int*   ei       = (const int*)d_in[1];
  const int*   ea       = (const int*)d_in[2];
  const int*   batch    = (const int*)d_in[3];
  const float* atom_emb = (const float*)d_in[4];
  const float* bond_emb = (const float*)d_in[5];
  const float* W        = (const float*)d_in[6];
  const float* b        = (const float*)d_in[7];
  const float* fc1_w    = (const float*)d_in[8];
  const float* fc1_b    = (const float*)d_in[9];
  const float* fc2_w    = (const float*)d_in[10];
  const float* fc2_b    = (const float*)d_in[11];
  float* out = (float*)d_out;

  char* p = (char*)d_ws;
  auto alloc = [&](size_t bytes) { char* r = p; p += (bytes + 255) & ~(size_t)255; return r; };
  float*          h0         = (float*)alloc((size_t)HN * 4);
  float*          h1         = (float*)alloc((size_t)HN * 4);
  unsigned short* h0_bf      = (unsigned short*)alloc((size_t)HN * 2);
  unsigned short* h1_bf      = (unsigned short*)alloc((size_t)HN * 2);
  unsigned short* t_bf       = (unsigned short*)alloc((size_t)N_NODES * TDIM * 2);
  unsigned short* wt         = (unsigned short*)alloc((size_t)3 * 128 * TDIM * 2);
  int*            gs         = (int*)alloc((size_t)(N_GRAPHS + 1) * 4);
  int*            deg        = (int*)alloc((size_t)N_NODES * 4);
  int*            row_start  = (int*)alloc((size_t)(N_NODES + 1) * 4);
  int*            cursor     = (int*)alloc((size_t)N_NODES * 4);
  int*            partials   = (int*)alloc(256 * 4);
  int2*           sorted_se  = (int2*)alloc((size_t)(N_EDGES + 8) * 8);

  hipMemsetAsync(deg, 0, N_NODES * sizeof(int), stream);
  const int pre_blocks = PRE_ATOM_NB + PRE_HIST_NB + PRE_WCONV_NB + PRE_GB_NB;
  k_pre<<<pre_blocks, 384, 0, stream>>>(x, atom_emb, h0, h0_bf, ei, deg, W, wt, batch, gs);
  k_scan_a<<<SCAN_NB, 256, 0, stream>>>(deg, row_start, partials);
  k_scan_b<<<1, 256, 0, stream>>>(partials, row_start);
  k_scan_c<<<SCAN_NB, 256, 0, stream>>>(row_start, partials, cursor);
  k_scatter<<<(N_EDGES + 255) / 256, 256, 0, stream>>>(ei, ea, cursor, sorted_se);

  float* hi = h0;  unsigned short* hib = h0_bf;
  float* ho = h1;  unsigned short* hob = h1_bf;
  const int gemm_blocks = (N_NODES + 31) / 32;  // 1563
  for (int layer = 0; layer < 3; ++layer) {
    k_agg<<<N_NODES / 8, 256, 0, stream>>>(sorted_se, row_start, bond_emb + layer * 72,
                                           hib, t_bf);
    k_gemm<<<gemm_blocks, 512, 0, stream>>>(
        t_bf, wt + (size_t)layer * 128 * TDIM, b + layer * 3 * EMB,
        hi, ho, hob, layer < 2 ? 1 : 0, layer < 2 ? 1 : 0);
    float* tf = hi; hi = ho; ho = tf;
    unsigned short* tb = hib; hib = hob; hob = tb;
  }
  // final h is in hi (h1 after 3 swaps)

  k_head<<<N_GRAPHS, 128, 0, stream>>>(hi, gs, fc1_w, fc1_b, fc2_w, fc2_b, out);
}

// Round 18
// 384.397 us; speedup vs baseline: 1.0190x; 1.0190x over previous
//
#include <hip/hip_runtime.h>

#define N_NODES 50000
#define N_EDGES 600000
#define N_GRAPHS 2048
#define EMB 128
#define TDIM 384
#define TS_LD 392               // padded LDS row stride (shorts): 2-way bank alias only
#define HN (N_NODES * EMB)
#define SCAN_NB ((N_NODES + 255) / 256)   // 196

// merged-prepass block ranges (384 threads/block)
#define PRE_ATOM_NB 4167        // 12 nodes/block, half-wave (32 lanes x float4) per node
#define PRE_HIST_NB 1563        // ceil(600000/384)
#define PRE_WCONV_NB 384        // one (layer,col) per block
#define PRE_GB_NB 131           // ceil(50000/384)

typedef __attribute__((ext_vector_type(8))) short bf16x8;
typedef __attribute__((ext_vector_type(4))) float f32x4;
#define MFMA_BF16(a, b, c) __builtin_amdgcn_mfma_f32_16x16x32_bf16(a, b, c, 0, 0, 0)

__device__ inline unsigned short f2bf(float f) {
  unsigned int u = __float_as_uint(f);
  u += 0x7fffu + ((u >> 16) & 1u);   // round to nearest even
  return (unsigned short)(u >> 16);
}
__device__ inline float bf2f(unsigned short b) {
  return __uint_as_float(((unsigned int)b) << 16);
}

// ---------------- merged prepass: atom-encoder | degree-hist | W-transpose | graph-bounds ----------
// Atom part re-granularized: half-wave (32 lanes x float4) per node -> 10 wave-instr
// slots per node instead of 40 (round-17's 128-thr/node was issue-bound at 52 us,
// HBM 15%, VALU 18% — pure instruction-count problem).
__global__ __launch_bounds__(384) void k_pre(const int* __restrict__ x,
                                             const float* __restrict__ atom_emb,
                                             float* __restrict__ h,
                                             unsigned short* __restrict__ h_bf,
                                             const int* __restrict__ ei,
                                             int* __restrict__ deg,
                                             const float* __restrict__ W,
                                             unsigned short* __restrict__ wt,
                                             const int* __restrict__ batch,
                                             int* __restrict__ gs) {
  int blk = blockIdx.x;
  if (blk < PRE_ATOM_NB) {
    int n = blk * 12 + (threadIdx.x >> 5);
    int sub = threadIdx.x & 31;     // cols sub*4..+3
    if (n < N_NODES) {
      const int* xr = x + n * 9;
      float4 acc = {0.f, 0.f, 0.f, 0.f};
#pragma unroll
      for (int c = 0; c < 9; ++c) {
        const float4* row = (const float4*)(atom_emb + (size_t)(c * 100 + xr[c]) * EMB);
        float4 v = row[sub];
        acc.x += v.x; acc.y += v.y; acc.z += v.z; acc.w += v.w;
      }
      *(float4*)(h + (size_t)n * EMB + sub * 4) = acc;
      *(ushort4*)(h_bf + (size_t)n * EMB + sub * 4) =
          ushort4{f2bf(acc.x), f2bf(acc.y), f2bf(acc.z), f2bf(acc.w)};
    }
    return;
  }
  blk -= PRE_ATOM_NB;
  if (blk < PRE_HIST_NB) {
    int e = blk * 384 + threadIdx.x;
    if (e < N_EDGES) atomicAdd(&deg[ei[N_EDGES + e]], 1);
    return;
  }
  blk -= PRE_HIST_NB;
  if (blk < PRE_WCONV_NB) {
    int layer = blk >> 7, c = blk & 127, k = threadIdx.x;
    float v = W[(((layer * 3 + (k >> 7)) * 128) + (k & 127)) * 128 + c];
    wt[(size_t)blk * 384 + k] = f2bf(v);
    return;
  }
  blk -= PRE_WCONV_NB;
  {
    int i = blk * 384 + threadIdx.x;
    if (i < N_NODES) {
      int b = batch[i];
      int bp = (i == 0) ? -1 : batch[i - 1];
      for (int g = bp + 1; g <= b; ++g) gs[g] = i;
      if (i == N_NODES - 1) {
        for (int g = b + 1; g <= N_GRAPHS; ++g) gs[g] = N_NODES;
      }
    }
  }
}

// ---------------- CSR scan ----------------
__global__ __launch_bounds__(256) void k_scan_a(const int* __restrict__ deg,
                                                int* __restrict__ row_start,
                                                int* __restrict__ partials) {
  __shared__ int s[256];
  const int tid = threadIdx.x;
  const int i = blockIdx.x * 256 + tid;
  int v = (i < N_NODES) ? deg[i] : 0;
  s[tid] = v;
  __syncthreads();
  for (int off = 1; off < 256; off <<= 1) {
    int t = (tid >= off) ? s[tid - off] : 0;
    __syncthreads();
    s[tid] += t;
    __syncthreads();
  }
  if (i < N_NODES) row_start[i] = s[tid] - v;
  if (tid == 255) partials[blockIdx.x] = s[255];
}

__global__ __launch_bounds__(256) void k_scan_b(int* __restrict__ partials,
                                                int* __restrict__ row_start) {
  __shared__ int s[256];
  const int tid = threadIdx.x;
  int v = (tid < SCAN_NB) ? partials[tid] : 0;
  s[tid] = v;
  __syncthreads();
  for (int off = 1; off < 256; off <<= 1) {
    int t = (tid >= off) ? s[tid - off] : 0;
    __syncthreads();
    s[tid] += t;
    __syncthreads();
  }
  if (tid < SCAN_NB) partials[tid] = s[tid] - v;
  if (tid == 255) row_start[N_NODES] = s[255];
}

__global__ __launch_bounds__(256) void k_scan_c(int* __restrict__ row_start,
                                                const int* __restrict__ partials,
                                                int* __restrict__ cursor) {
  const int i = blockIdx.x * 256 + threadIdx.x;
  if (i < N_NODES) {
    int r = row_start[i] + partials[blockIdx.x];
    row_start[i] = r;
    cursor[i] = r;
  }
}

// Scatter edges into CSR order: one int2{src, packed_attr} per edge.
__global__ __launch_bounds__(256) void k_scatter(const int* __restrict__ ei,
                                                 const int* __restrict__ ea,
                                                 int* __restrict__ cursor,
                                                 int2* __restrict__ sorted_se) {
  int e = blockIdx.x * 256 + threadIdx.x;
  if (e >= N_EDGES) return;
  int src = ei[e], dst = ei[N_EDGES + e];
  int pos = atomicAdd(&cursor[dst], 1);
  int eap = ea[e * 3 + 0] | (ea[e * 3 + 1] << 3) | (ea[e * 3 + 2] << 6);
  sorted_se[pos] = int2{src, eap};
}

// ---------------- Edge aggregation (2 nodes/wave, ushort4, unroll-8, LDS combo) ----------------
__global__ __launch_bounds__(256) void k_agg(const int2* __restrict__ sorted_se,
                                             const int* __restrict__ row_start,
                                             const float* __restrict__ bl,  // bond_emb[layer]: [3][8][3]
                                             const unsigned short* __restrict__ h_bf,
                                             unsigned short* __restrict__ t_bf) {
  __shared__ float4 combo[512];  // 8 KB
  for (int c = threadIdx.x; c < 512; c += 256) {
    int a0 = c & 7, a1 = (c >> 3) & 7, a2 = (c >> 6) & 7;
    combo[c] = float4{bl[a0 * 3 + 0] + bl[24 + a1 * 3 + 0] + bl[48 + a2 * 3 + 0],
                      bl[a0 * 3 + 1] + bl[24 + a1 * 3 + 1] + bl[48 + a2 * 3 + 1],
                      bl[a0 * 3 + 2] + bl[24 + a1 * 3 + 2] + bl[48 + a2 * 3 + 2], 0.f};
  }
  __syncthreads();
  const int node = blockIdx.x * 8 + (threadIdx.x >> 5);  // half-wave per node
  const int sub = threadIdx.x & 31;                      // cols sub*4..+3
  const int beg = row_start[node], end = row_start[node + 1];
  float4 a0 = {0.f, 0.f, 0.f, 0.f}, a1 = a0, a2 = a0;
  for (int e = beg; e < end; e += 8) {
    int2 se[8];
#pragma unroll
    for (int i = 0; i < 8; ++i) {
      int idx = e + i;
      se[i] = sorted_se[idx < end ? idx : end - 1];
    }
    ushort4 u[8];
#pragma unroll
    for (int i = 0; i < 8; ++i)
      u[i] = *(const ushort4*)(h_bf + (size_t)se[i].x * EMB + sub * 4);
#pragma unroll
    for (int i = 0; i < 8; ++i) {
      float4 w = (e + i < end) ? combo[se[i].y] : float4{0.f, 0.f, 0.f, 0.f};
      float4 vf = {bf2f(u[i].x), bf2f(u[i].y), bf2f(u[i].z), bf2f(u[i].w)};
      a0 += vf * w.x;
      a1 += vf * w.y;
      a2 += vf * w.z;
    }
  }
  size_t base = (size_t)node * TDIM + sub * 4;
  *(ushort4*)(t_bf + base)       = ushort4{f2bf(a0.x), f2bf(a0.y), f2bf(a0.z), f2bf(a0.w)};
  *(ushort4*)(t_bf + base + 128) = ushort4{f2bf(a1.x), f2bf(a1.y), f2bf(a1.z), f2bf(a1.w)};
  *(ushort4*)(t_bf + base + 256) = ushort4{f2bf(a2.x), f2bf(a2.y), f2bf(a2.z), f2bf(a2.w)};
}

// ---------------- MFMA GEMM: stage 32 t-rows into LDS (coalesced), then per-wave GEMM ----------------
// Block 512 thr = 8 waves; 32 nodes/block; grid 1563. Wave wv owns cols wv*16..+15:
// 12 resident B-frags, 2 row-tiles (A via ds_read_b128), 12 chained MFMAs each,
// inline bias+relu+residual epilogue. h ping-pong (gather safety).
// A-frag: A[m=lane&15][k=(lane>>4)*8+j]; B-frag: B[k][n=lane&15];
// C/D: col=lane&15, row=(lane>>4)*4+reg.
__global__ __launch_bounds__(512) void k_gemm(const unsigned short* __restrict__ t_bf,
                                              const unsigned short* __restrict__ wt,  // [128][384]
                                              const float* __restrict__ bl,  // [3][128]
                                              const float* __restrict__ h_in,
                                              float* __restrict__ h_out,
                                              unsigned short* __restrict__ h_out_bf,
                                              int do_relu, int write_bf) {
  __shared__ unsigned short ts[32 * TS_LD];   // 24.5 KB
  const int nb = blockIdx.x * 32;
  for (int i = threadIdx.x; i < 32 * 48; i += 512) {
    int r = i / 48, cc = i % 48;
    bf16x8 v = {};
    int row = nb + r;
    if (row < N_NODES) v = *(const bf16x8*)(t_bf + (size_t)row * TDIM + cc * 8);
    *(bf16x8*)(ts + r * TS_LD + cc * 8) = v;
  }
  __syncthreads();

  const int wv = threadIdx.x >> 6;
  const int lane = threadIdx.x & 63;
  const int m = lane & 15;
  const int kq = lane >> 4;
  const int c = wv * 16 + m;

  const unsigned short* pB = wt + (size_t)c * TDIM + kq * 8;
  bf16x8 B[12];
#pragma unroll
  for (int kc = 0; kc < 12; ++kc) B[kc] = *(const bf16x8*)(pB + kc * 32);

  const float bias = bl[c] + bl[128 + c] + bl[256 + c];

#pragma unroll
  for (int rt = 0; rt < 2; ++rt) {
    const unsigned short* pA = ts + (rt * 16 + m) * TS_LD + kq * 8;
    bf16x8 A[12];
#pragma unroll
    for (int kc = 0; kc < 12; ++kc) A[kc] = *(const bf16x8*)(pA + kc * 32);
    f32x4 acc = {0.f, 0.f, 0.f, 0.f};
#pragma unroll
    for (int kc = 0; kc < 12; ++kc) acc = MFMA_BF16(A[kc], B[kc], acc);
#pragma unroll
    for (int r = 0; r < 4; ++r) {
      int row = nb + rt * 16 + kq * 4 + r;
      if (row < N_NODES) {
        size_t idx = (size_t)row * EMB + c;
        float v = acc[r] + bias;
        if (do_relu) v = fmaxf(v, 0.f);
        float hn = h_in[idx] + v;
        h_out[idx] = hn;
        if (write_bf) h_out_bf[idx] = f2bf(hn);
      }
    }
  }
}

// ---------------- fused mean-pool + head: block g reduces its contiguous node range ----------------
__global__ __launch_bounds__(128) void k_head(const float* __restrict__ h,
                                              const int* __restrict__ gs,
                                              const float* __restrict__ fc1_w,
                                              const float* __restrict__ fc1_b,
                                              const float* __restrict__ fc2_w,
                                              const float* __restrict__ fc2_b,
                                              float* __restrict__ out) {
  __shared__ float hg[EMB];
  __shared__ float red[EMB];
  int g = blockIdx.x, e = threadIdx.x;
  int ns = gs[g], ne = gs[g + 1];
  float acc = 0.f;
  for (int n = ns; n < ne; ++n) acc += h[(size_t)n * EMB + e];
  float cnt = fmaxf((float)(ne - ns), 1.f);
  hg[e] = acc / cnt;
  __syncthreads();
  float a2 = fc1_b[e];
  for (int j = 0; j < EMB; ++j) a2 += hg[j] * fc1_w[j * EMB + e];
  red[e] = a2 * fc2_w[e];
  __syncthreads();
  for (int s = 64; s > 0; s >>= 1) {
    if (e < s) red[e] += red[e + s];
    __syncthreads();
  }
  if (e == 0) out[g] = red[0] + fc2_b[0];
}

extern "C" void kernel_launch(void* const* d_in, const int* in_sizes, int n_in,
                              void* d_out, int out_size, void* d_ws, size_t ws_size,
                              hipStream_t stream) {
  const int*   x        = (const int*)d_in[0];
  const int*   ei       = (const int*)d_in[1];
  const int*   ea       = (const int*)d_in[2];
  const int*   batch    = (const int*)d_in[3];
  const float* atom_emb = (const float*)d_in[4];
  const float* bond_emb = (const float*)d_in[5];
  const float* W        = (const float*)d_in[6];
  const float* b        = (const float*)d_in[7];
  const float* fc1_w    = (const float*)d_in[8];
  const float* fc1_b    = (const float*)d_in[9];
  const float* fc2_w    = (const float*)d_in[10];
  const float* fc2_b    = (const float*)d_in[11];
  float* out = (float*)d_out;

  char* p = (char*)d_ws;
  auto alloc = [&](size_t bytes) { char* r = p; p += (bytes + 255) & ~(size_t)255; return r; };
  float*          h0         = (float*)alloc((size_t)HN * 4);
  float*          h1         = (float*)alloc((size_t)HN * 4);
  unsigned short* h0_bf      = (unsigned short*)alloc((size_t)HN * 2);
  unsigned short* h1_bf      = (unsigned short*)alloc((size_t)HN * 2);
  unsigned short* t_bf       = (unsigned short*)alloc((size_t)N_NODES * TDIM * 2);
  unsigned short* wt         = (unsigned short*)alloc((size_t)3 * 128 * TDIM * 2);
  int*            gs         = (int*)alloc((size_t)(N_GRAPHS + 1) * 4);
  int*            deg        = (int*)alloc((size_t)N_NODES * 4);
  int*            row_start  = (int*)alloc((size_t)(N_NODES + 1) * 4);
  int*            cursor     = (int*)alloc((size_t)N_NODES * 4);
  int*            partials   = (int*)alloc(256 * 4);
  int2*           sorted_se  = (int2*)alloc((size_t)(N_EDGES + 8) * 8);

  hipMemsetAsync(deg, 0, N_NODES * sizeof(int), stream);
  const int pre_blocks = PRE_ATOM_NB + PRE_HIST_NB + PRE_WCONV_NB + PRE_GB_NB;
  k_pre<<<pre_blocks, 384, 0, stream>>>(x, atom_emb, h0, h0_bf, ei, deg, W, wt, batch, gs);
  k_scan_a<<<SCAN_NB, 256, 0, stream>>>(deg, row_start, partials);
  k_scan_b<<<1, 256, 0, stream>>>(partials, row_start);
  k_scan_c<<<SCAN_NB, 256, 0, stream>>>(row_start, partials, cursor);
  k_scatter<<<(N_EDGES + 255) / 256, 256, 0, stream>>>(ei, ea, cursor, sorted_se);

  float* hi = h0;  unsigned short* hib = h0_bf;
  float* ho = h1;  unsigned short* hob = h1_bf;
  const int gemm_blocks = (N_NODES + 31) / 32;  // 1563
  for (int layer = 0; layer < 3; ++layer) {
    k_agg<<<N_NODES / 8, 256, 0, stream>>>(sorted_se, row_start, bond_emb + layer * 72,
                                           hib, t_bf);
    k_gemm<<<gemm_blocks, 512, 0, stream>>>(
        t_bf, wt + (size_t)layer * 128 * TDIM, b + layer * 3 * EMB,
        hi, ho, hob, layer < 2 ? 1 : 0, layer < 2 ? 1 : 0);
    float* tf = hi; hi = ho; ho = tf;
    unsigned short* tb = hib; hib = hob; hob = tb;
  }
  // final h is in hi (h1 after 3 swaps)

  k_head<<<N_GRAPHS, 128, 0, stream>>>(hi, gs, fc1_w, fc1_b, fc2_w, fc2_b, out);
}

// Round 19
// 375.190 us; speedup vs baseline: 1.0440x; 1.0245x over previous
//
#include <hip/hip_runtime.h>

#define N_NODES 50000
#define N_EDGES 600000
#define N_GRAPHS 2048
#define EMB 128
#define TDIM 384
#define TS_LD 392               // padded LDS row stride (shorts): 2-way bank alias only
#define HN (N_NODES * EMB)
#define SCAN_NB ((N_NODES + 255) / 256)   // 196

// merged-prepass block ranges (384 threads/block)
#define PRE_ATOM_NB 4167        // 12 nodes/block, half-wave (32 lanes x float4) per node
#define PRE_HIST_NB 1563        // ceil(600000/384)
#define PRE_WCONV_NB 384        // one (layer,col) per block
#define PRE_GB_NB 131           // ceil(50000/384)

typedef __attribute__((ext_vector_type(8))) short bf16x8;
typedef __attribute__((ext_vector_type(4))) float f32x4;
#define MFMA_BF16(a, b, c) __builtin_amdgcn_mfma_f32_16x16x32_bf16(a, b, c, 0, 0, 0)

__device__ inline unsigned short f2bf(float f) {
  unsigned int u = __float_as_uint(f);
  u += 0x7fffu + ((u >> 16) & 1u);   // round to nearest even
  return (unsigned short)(u >> 16);
}
__device__ inline float bf2f(unsigned short b) {
  return __uint_as_float(((unsigned int)b) << 16);
}

// ---------------- merged prepass: atom-encoder | degree-hist | W-transpose | graph-bounds ----------
// h lives ONLY as bf16 now (round-19: fp32 residual shadow dropped — it cost
// 51 MB/layer in k_gemm + 25.6 MB write here; bf16 residual rounding adds ~2^-9
// relative error per layer, budgeted under the 0.0252 threshold).
__global__ __launch_bounds__(384) void k_pre(const int* __restrict__ x,
                                             const float* __restrict__ atom_emb,
                                             unsigned short* __restrict__ h_bf,
                                             const int* __restrict__ ei,
                                             int* __restrict__ deg,
                                             const float* __restrict__ W,
                                             unsigned short* __restrict__ wt,
                                             const int* __restrict__ batch,
                                             int* __restrict__ gs) {
  int blk = blockIdx.x;
  if (blk < PRE_ATOM_NB) {
    int n = blk * 12 + (threadIdx.x >> 5);
    int sub = threadIdx.x & 31;     // cols sub*4..+3
    if (n < N_NODES) {
      const int* xr = x + n * 9;
      float4 acc = {0.f, 0.f, 0.f, 0.f};
#pragma unroll
      for (int c = 0; c < 9; ++c) {
        const float4* row = (const float4*)(atom_emb + (size_t)(c * 100 + xr[c]) * EMB);
        float4 v = row[sub];
        acc.x += v.x; acc.y += v.y; acc.z += v.z; acc.w += v.w;
      }
      *(ushort4*)(h_bf + (size_t)n * EMB + sub * 4) =
          ushort4{f2bf(acc.x), f2bf(acc.y), f2bf(acc.z), f2bf(acc.w)};
    }
    return;
  }
  blk -= PRE_ATOM_NB;
  if (blk < PRE_HIST_NB) {
    int e = blk * 384 + threadIdx.x;
    if (e < N_EDGES) atomicAdd(&deg[ei[N_EDGES + e]], 1);
    return;
  }
  blk -= PRE_HIST_NB;
  if (blk < PRE_WCONV_NB) {
    int layer = blk >> 7, c = blk & 127, k = threadIdx.x;
    float v = W[(((layer * 3 + (k >> 7)) * 128) + (k & 127)) * 128 + c];
    wt[(size_t)blk * 384 + k] = f2bf(v);
    return;
  }
  blk -= PRE_WCONV_NB;
  {
    int i = blk * 384 + threadIdx.x;
    if (i < N_NODES) {
      int b = batch[i];
      int bp = (i == 0) ? -1 : batch[i - 1];
      for (int g = bp + 1; g <= b; ++g) gs[g] = i;
      if (i == N_NODES - 1) {
        for (int g = b + 1; g <= N_GRAPHS; ++g) gs[g] = N_NODES;
      }
    }
  }
}

// ---------------- CSR scan ----------------
__global__ __launch_bounds__(256) void k_scan_a(const int* __restrict__ deg,
                                                int* __restrict__ row_start,
                                                int* __restrict__ partials) {
  __shared__ int s[256];
  const int tid = threadIdx.x;
  const int i = blockIdx.x * 256 + tid;
  int v = (i < N_NODES) ? deg[i] : 0;
  s[tid] = v;
  __syncthreads();
  for (int off = 1; off < 256; off <<= 1) {
    int t = (tid >= off) ? s[tid - off] : 0;
    __syncthreads();
    s[tid] += t;
    __syncthreads();
  }
  if (i < N_NODES) row_start[i] = s[tid] - v;
  if (tid == 255) partials[blockIdx.x] = s[255];
}

__global__ __launch_bounds__(256) void k_scan_b(int* __restrict__ partials,
                                                int* __restrict__ row_start) {
  __shared__ int s[256];
  const int tid = threadIdx.x;
  int v = (tid < SCAN_NB) ? partials[tid] : 0;
  s[tid] = v;
  __syncthreads();
  for (int off = 1; off < 256; off <<= 1) {
    int t = (tid >= off) ? s[tid - off] : 0;
    __syncthreads();
    s[tid] += t;
    __syncthreads();
  }
  if (tid < SCAN_NB) partials[tid] = s[tid] - v;
  if (tid == 255) row_start[N_NODES] = s[255];
}

__global__ __launch_bounds__(256) void k_scan_c(int* __restrict__ row_start,
                                                const int* __restrict__ partials,
                                                int* __restrict__ cursor) {
  const int i = blockIdx.x * 256 + threadIdx.x;
  if (i < N_NODES) {
    int r = row_start[i] + partials[blockIdx.x];
    row_start[i] = r;
    cursor[i] = r;
  }
}

// Scatter edges into CSR order: one int2{src, packed_attr} per edge.
__global__ __launch_bounds__(256) void k_scatter(const int* __restrict__ ei,
                                                 const int* __restrict__ ea,
                                                 int* __restrict__ cursor,
                                                 int2* __restrict__ sorted_se) {
  int e = blockIdx.x * 256 + threadIdx.x;
  if (e >= N_EDGES) return;
  int src = ei[e], dst = ei[N_EDGES + e];
  int pos = atomicAdd(&cursor[dst], 1);
  int eap = ea[e * 3 + 0] | (ea[e * 3 + 1] << 3) | (ea[e * 3 + 2] << 6);
  sorted_se[pos] = int2{src, eap};
}

// ---------------- Edge aggregation (2 nodes/wave, ushort4, unroll-8, LDS combo) ----------------
__global__ __launch_bounds__(256) void k_agg(const int2* __restrict__ sorted_se,
                                             const int* __restrict__ row_start,
                                             const float* __restrict__ bl,  // bond_emb[layer]: [3][8][3]
                                             const unsigned short* __restrict__ h_bf,
                                             unsigned short* __restrict__ t_bf) {
  __shared__ float4 combo[512];  // 8 KB
  for (int c = threadIdx.x; c < 512; c += 256) {
    int a0 = c & 7, a1 = (c >> 3) & 7, a2 = (c >> 6) & 7;
    combo[c] = float4{bl[a0 * 3 + 0] + bl[24 + a1 * 3 + 0] + bl[48 + a2 * 3 + 0],
                      bl[a0 * 3 + 1] + bl[24 + a1 * 3 + 1] + bl[48 + a2 * 3 + 1],
                      bl[a0 * 3 + 2] + bl[24 + a1 * 3 + 2] + bl[48 + a2 * 3 + 2], 0.f};
  }
  __syncthreads();
  const int node = blockIdx.x * 8 + (threadIdx.x >> 5);  // half-wave per node
  const int sub = threadIdx.x & 31;                      // cols sub*4..+3
  const int beg = row_start[node], end = row_start[node + 1];
  float4 a0 = {0.f, 0.f, 0.f, 0.f}, a1 = a0, a2 = a0;
  for (int e = beg; e < end; e += 8) {
    int2 se[8];
#pragma unroll
    for (int i = 0; i < 8; ++i) {
      int idx = e + i;
      se[i] = sorted_se[idx < end ? idx : end - 1];
    }
    ushort4 u[8];
#pragma unroll
    for (int i = 0; i < 8; ++i)
      u[i] = *(const ushort4*)(h_bf + (size_t)se[i].x * EMB + sub * 4);
#pragma unroll
    for (int i = 0; i < 8; ++i) {
      float4 w = (e + i < end) ? combo[se[i].y] : float4{0.f, 0.f, 0.f, 0.f};
      float4 vf = {bf2f(u[i].x), bf2f(u[i].y), bf2f(u[i].z), bf2f(u[i].w)};
      a0 += vf * w.x;
      a1 += vf * w.y;
      a2 += vf * w.z;
    }
  }
  size_t base = (size_t)node * TDIM + sub * 4;
  *(ushort4*)(t_bf + base)       = ushort4{f2bf(a0.x), f2bf(a0.y), f2bf(a0.z), f2bf(a0.w)};
  *(ushort4*)(t_bf + base + 128) = ushort4{f2bf(a1.x), f2bf(a1.y), f2bf(a1.z), f2bf(a1.w)};
  *(ushort4*)(t_bf + base + 256) = ushort4{f2bf(a2.x), f2bf(a2.y), f2bf(a2.z), f2bf(a2.w)};
}

// ---------------- MFMA GEMM: stage 32 t-rows into LDS, per-wave GEMM, bf16 residual ----------------
// Block 512 thr = 8 waves; 32 nodes/block; grid 1563. Wave wv owns cols wv*16..+15:
// 12 resident B-frags, 2 row-tiles (A via ds_read_b128), 12 chained MFMAs each.
// Epilogue: bias+relu + bf16 residual (h_in_bf read, h_out_bf written — no fp32 h).
// A-frag: A[m=lane&15][k=(lane>>4)*8+j]; B-frag: B[k][n=lane&15];
// C/D: col=lane&15, row=(lane>>4)*4+reg.
__global__ __launch_bounds__(512) void k_gemm(const unsigned short* __restrict__ t_bf,
                                              const unsigned short* __restrict__ wt,  // [128][384]
                                              const float* __restrict__ bl,  // [3][128]
                                              const unsigned short* __restrict__ h_in_bf,
                                              unsigned short* __restrict__ h_out_bf,
                                              int do_relu) {
  __shared__ unsigned short ts[32 * TS_LD];   // 24.5 KB
  const int nb = blockIdx.x * 32;
  for (int i = threadIdx.x; i < 32 * 48; i += 512) {
    int r = i / 48, cc = i % 48;
    bf16x8 v = {};
    int row = nb + r;
    if (row < N_NODES) v = *(const bf16x8*)(t_bf + (size_t)row * TDIM + cc * 8);
    *(bf16x8*)(ts + r * TS_LD + cc * 8) = v;
  }
  __syncthreads();

  const int wv = threadIdx.x >> 6;
  const int lane = threadIdx.x & 63;
  const int m = lane & 15;
  const int kq = lane >> 4;
  const int c = wv * 16 + m;

  const unsigned short* pB = wt + (size_t)c * TDIM + kq * 8;
  bf16x8 B[12];
#pragma unroll
  for (int kc = 0; kc < 12; ++kc) B[kc] = *(const bf16x8*)(pB + kc * 32);

  const float bias = bl[c] + bl[128 + c] + bl[256 + c];

#pragma unroll
  for (int rt = 0; rt < 2; ++rt) {
    const unsigned short* pA = ts + (rt * 16 + m) * TS_LD + kq * 8;
    bf16x8 A[12];
#pragma unroll
    for (int kc = 0; kc < 12; ++kc) A[kc] = *(const bf16x8*)(pA + kc * 32);
    f32x4 acc = {0.f, 0.f, 0.f, 0.f};
#pragma unroll
    for (int kc = 0; kc < 12; ++kc) acc = MFMA_BF16(A[kc], B[kc], acc);
#pragma unroll
    for (int r = 0; r < 4; ++r) {
      int row = nb + rt * 16 + kq * 4 + r;
      if (row < N_NODES) {
        size_t idx = (size_t)row * EMB + c;
        float v = acc[r] + bias;
        if (do_relu) v = fmaxf(v, 0.f);
        float hn = bf2f(h_in_bf[idx]) + v;
        h_out_bf[idx] = f2bf(hn);
      }
    }
  }
}

// ---------------- fused mean-pool + head: block g reduces its contiguous node range ----------------
__global__ __launch_bounds__(128) void k_head(const unsigned short* __restrict__ h_bf,
                                              const int* __restrict__ gs,
                                              const float* __restrict__ fc1_w,
                                              const float* __restrict__ fc1_b,
                                              const float* __restrict__ fc2_w,
                                              const float* __restrict__ fc2_b,
                                              float* __restrict__ out) {
  __shared__ float hg[EMB];
  __shared__ float red[EMB];
  int g = blockIdx.x, e = threadIdx.x;
  int ns = gs[g], ne = gs[g + 1];
  float acc = 0.f;
  for (int n = ns; n < ne; ++n) acc += bf2f(h_bf[(size_t)n * EMB + e]);
  float cnt = fmaxf((float)(ne - ns), 1.f);
  hg[e] = acc / cnt;
  __syncthreads();
  float a2 = fc1_b[e];
  for (int j = 0; j < EMB; ++j) a2 += hg[j] * fc1_w[j * EMB + e];
  red[e] = a2 * fc2_w[e];
  __syncthreads();
  for (int s = 64; s > 0; s >>= 1) {
    if (e < s) red[e] += red[e + s];
    __syncthreads();
  }
  if (e == 0) out[g] = red[0] + fc2_b[0];
}

extern "C" void kernel_launch(void* const* d_in, const int* in_sizes, int n_in,
                              void* d_out, int out_size, void* d_ws, size_t ws_size,
                              hipStream_t stream) {
  const int*   x        = (const int*)d_in[0];
  const int*   ei       = (const int*)d_in[1];
  const int*   ea       = (const int*)d_in[2];
  const int*   batch    = (const int*)d_in[3];
  const float* atom_emb = (const float*)d_in[4];
  const float* bond_emb = (const float*)d_in[5];
  const float* W        = (const float*)d_in[6];
  const float* b        = (const float*)d_in[7];
  const float* fc1_w    = (const float*)d_in[8];
  const float* fc1_b    = (const float*)d_in[9];
  const float* fc2_w    = (const float*)d_in[10];
  const float* fc2_b    = (const float*)d_in[11];
  float* out = (float*)d_out;

  char* p = (char*)d_ws;
  auto alloc = [&](size_t bytes) { char* r = p; p += (bytes + 255) & ~(size_t)255; return r; };
  unsigned short* h0_bf      = (unsigned short*)alloc((size_t)HN * 2);
  unsigned short* h1_bf      = (unsigned short*)alloc((size_t)HN * 2);
  unsigned short* t_bf       = (unsigned short*)alloc((size_t)N_NODES * TDIM * 2);
  unsigned short* wt         = (unsigned short*)alloc((size_t)3 * 128 * TDIM * 2);
  int*            gs         = (int*)alloc((size_t)(N_GRAPHS + 1) * 4);
  int*            deg        = (int*)alloc((size_t)N_NODES * 4);
  int*            row_start  = (int*)alloc((size_t)(N_NODES + 1) * 4);
  int*            cursor     = (int*)alloc((size_t)N_NODES * 4);
  int*            partials   = (int*)alloc(256 * 4);
  int2*           sorted_se  = (int2*)alloc((size_t)(N_EDGES + 8) * 8);

  hipMemsetAsync(deg, 0, N_NODES * sizeof(int), stream);
  const int pre_blocks = PRE_ATOM_NB + PRE_HIST_NB + PRE_WCONV_NB + PRE_GB_NB;
  k_pre<<<pre_blocks, 384, 0, stream>>>(x, atom_emb, h0_bf, ei, deg, W, wt, batch, gs);
  k_scan_a<<<SCAN_NB, 256, 0, stream>>>(deg, row_start, partials);
  k_scan_b<<<1, 256, 0, stream>>>(partials, row_start);
  k_scan_c<<<SCAN_NB, 256, 0, stream>>>(row_start, partials, cursor);
  k_scatter<<<(N_EDGES + 255) / 256, 256, 0, stream>>>(ei, ea, cursor, sorted_se);

  unsigned short* hib = h0_bf;
  unsigned short* hob = h1_bf;
  const int gemm_blocks = (N_NODES + 31) / 32;  // 1563
  for (int layer = 0; layer < 3; ++layer) {
    k_agg<<<N_NODES / 8, 256, 0, stream>>>(sorted_se, row_start, bond_emb + layer * 72,
                                           hib, t_bf);
    k_gemm<<<gemm_blocks, 512, 0, stream>>>(
        t_bf, wt + (size_t)layer * 128 * TDIM, b + layer * 3 * EMB,
        hib, hob, layer < 2 ? 1 : 0);
    unsigned short* tb = hib; hib = hob; hob = tb;
  }
  // final h is in hib (h1_bf after 3 swaps)

  k_head<<<N_GRAPHS, 128, 0, stream>>>(hib, gs, fc1_w, fc1_b, fc2_w, fc2_b, out);
}

// Round 20
// 369.235 us; speedup vs baseline: 1.0608x; 1.0161x over previous
//
#include <hip/hip_runtime.h>

#define N_NODES 50000
#define N_EDGES 600000
#define N_GRAPHS 2048
#define EMB 128
#define TDIM 384
#define TS_LD 392               // padded LDS row stride (shorts): 2-way bank alias only
#define HN (N_NODES * EMB)
#define SCAN_NB ((N_NODES + 255) / 256)   // 196

// merged-prepass block ranges (384 threads/block)
#define PRE_ATOM_NB 8334        // 6 nodes/block, FULL wave (64 lanes x float2) per node
#define PRE_HIST_NB 1563        // ceil(600000/384)
#define PRE_WCONV_NB 384        // one (layer,col) per block
#define PRE_GB_NB 131           // ceil(50000/384)

typedef __attribute__((ext_vector_type(8))) short bf16x8;
typedef __attribute__((ext_vector_type(4))) float f32x4;
#define MFMA_BF16(a, b, c) __builtin_amdgcn_mfma_f32_16x16x32_bf16(a, b, c, 0, 0, 0)

__device__ inline unsigned short f2bf(float f) {
  unsigned int u = __float_as_uint(f);
  u += 0x7fffu + ((u >> 16) & 1u);   // round to nearest even
  return (unsigned short)(u >> 16);
}
__device__ inline float bf2f(unsigned short b) {
  return __uint_as_float(((unsigned int)b) << 16);
}

// ---------------- merged prepass: atom-encoder | degree-hist | W-transpose | graph-bounds ----------
// Atom part: FULL wave per node -> n is wave-uniform, so the 9 x-row reads become
// SCALAR (s_load) via readfirstlane, off the VMEM pipe entirely. Per node:
// 9 vector gathers (512 B each) + 1 store — ~10 VMEM issues vs round-19's 20.
__global__ __launch_bounds__(384) void k_pre(const int* __restrict__ x,
                                             const float* __restrict__ atom_emb,
                                             unsigned short* __restrict__ h_bf,
                                             const int* __restrict__ ei,
                                             int* __restrict__ deg,
                                             const float* __restrict__ W,
                                             unsigned short* __restrict__ wt,
                                             const int* __restrict__ batch,
                                             int* __restrict__ gs) {
  int blk = blockIdx.x;
  if (blk < PRE_ATOM_NB) {
    int n = blk * 6 + (threadIdx.x >> 6);
    int lane = threadIdx.x & 63;    // covers cols lane*2, lane*2+1
    if (n < N_NODES) {
      const int nu = __builtin_amdgcn_readfirstlane(n);
      const int* xr = x + nu * 9;
      float2 acc = {0.f, 0.f};
#pragma unroll
      for (int c = 0; c < 9; ++c) {
        const float2* row = (const float2*)(atom_emb + (size_t)(c * 100 + xr[c]) * EMB);
        float2 v = row[lane];
        acc.x += v.x; acc.y += v.y;
      }
      *(ushort2*)(h_bf + (size_t)nu * EMB + lane * 2) = ushort2{f2bf(acc.x), f2bf(acc.y)};
    }
    return;
  }
  blk -= PRE_ATOM_NB;
  if (blk < PRE_HIST_NB) {
    int e = blk * 384 + threadIdx.x;
    if (e < N_EDGES) atomicAdd(&deg[ei[N_EDGES + e]], 1);
    return;
  }
  blk -= PRE_HIST_NB;
  if (blk < PRE_WCONV_NB) {
    int layer = blk >> 7, c = blk & 127, k = threadIdx.x;
    float v = W[(((layer * 3 + (k >> 7)) * 128) + (k & 127)) * 128 + c];
    wt[(size_t)blk * 384 + k] = f2bf(v);
    return;
  }
  blk -= PRE_WCONV_NB;
  {
    int i = blk * 384 + threadIdx.x;
    if (i < N_NODES) {
      int b = batch[i];
      int bp = (i == 0) ? -1 : batch[i - 1];
      for (int g = bp + 1; g <= b; ++g) gs[g] = i;
      if (i == N_NODES - 1) {
        for (int g = b + 1; g <= N_GRAPHS; ++g) gs[g] = N_NODES;
      }
    }
  }
}

// ---------------- CSR scan ----------------
__global__ __launch_bounds__(256) void k_scan_a(const int* __restrict__ deg,
                                                int* __restrict__ row_start,
                                                int* __restrict__ partials) {
  __shared__ int s[256];
  const int tid = threadIdx.x;
  const int i = blockIdx.x * 256 + tid;
  int v = (i < N_NODES) ? deg[i] : 0;
  s[tid] = v;
  __syncthreads();
  for (int off = 1; off < 256; off <<= 1) {
    int t = (tid >= off) ? s[tid - off] : 0;
    __syncthreads();
    s[tid] += t;
    __syncthreads();
  }
  if (i < N_NODES) row_start[i] = s[tid] - v;
  if (tid == 255) partials[blockIdx.x] = s[255];
}

__global__ __launch_bounds__(256) void k_scan_b(int* __restrict__ partials,
                                                int* __restrict__ row_start) {
  __shared__ int s[256];
  const int tid = threadIdx.x;
  int v = (tid < SCAN_NB) ? partials[tid] : 0;
  s[tid] = v;
  __syncthreads();
  for (int off = 1; off < 256; off <<= 1) {
    int t = (tid >= off) ? s[tid - off] : 0;
    __syncthreads();
    s[tid] += t;
    __syncthreads();
  }
  if (tid < SCAN_NB) partials[tid] = s[tid] - v;
  if (tid == 255) row_start[N_NODES] = s[255];
}

__global__ __launch_bounds__(256) void k_scan_c(int* __restrict__ row_start,
                                                const int* __restrict__ partials,
                                                int* __restrict__ cursor) {
  const int i = blockIdx.x * 256 + threadIdx.x;
  if (i < N_NODES) {
    int r = row_start[i] + partials[blockIdx.x];
    row_start[i] = r;
    cursor[i] = r;
  }
}

// Scatter edges into CSR order: one int2{src, packed_attr} per edge.
__global__ __launch_bounds__(256) void k_scatter(const int* __restrict__ ei,
                                                 const int* __restrict__ ea,
                                                 int* __restrict__ cursor,
                                                 int2* __restrict__ sorted_se) {
  int e = blockIdx.x * 256 + threadIdx.x;
  if (e >= N_EDGES) return;
  int src = ei[e], dst = ei[N_EDGES + e];
  int pos = atomicAdd(&cursor[dst], 1);
  int eap = ea[e * 3 + 0] | (ea[e * 3 + 1] << 3) | (ea[e * 3 + 2] << 6);
  sorted_se[pos] = int2{src, eap};
}

// ---------------- Edge aggregation (2 nodes/wave, ushort4, unroll-8, LDS combo) ----------------
// Full 8-chunks run an UNCHECKED fast path (no index clamp, no weight select);
// only the final partial chunk pays bounds logic.
__global__ __launch_bounds__(256) void k_agg(const int2* __restrict__ sorted_se,
                                             const int* __restrict__ row_start,
                                             const float* __restrict__ bl,  // bond_emb[layer]: [3][8][3]
                                             const unsigned short* __restrict__ h_bf,
                                             unsigned short* __restrict__ t_bf) {
  __shared__ float4 combo[512];  // 8 KB
  for (int c = threadIdx.x; c < 512; c += 256) {
    int a0 = c & 7, a1 = (c >> 3) & 7, a2 = (c >> 6) & 7;
    combo[c] = float4{bl[a0 * 3 + 0] + bl[24 + a1 * 3 + 0] + bl[48 + a2 * 3 + 0],
                      bl[a0 * 3 + 1] + bl[24 + a1 * 3 + 1] + bl[48 + a2 * 3 + 1],
                      bl[a0 * 3 + 2] + bl[24 + a1 * 3 + 2] + bl[48 + a2 * 3 + 2], 0.f};
  }
  __syncthreads();
  const int node = blockIdx.x * 8 + (threadIdx.x >> 5);  // half-wave per node
  const int sub = threadIdx.x & 31;                      // cols sub*4..+3
  const int beg = row_start[node], end = row_start[node + 1];
  float4 a0 = {0.f, 0.f, 0.f, 0.f}, a1 = a0, a2 = a0;
  int e = beg;
  const int full_end = beg + ((end - beg) & ~7);
  for (; e < full_end; e += 8) {           // fast path: no bounds logic
    int2 se[8];
#pragma unroll
    for (int i = 0; i < 8; ++i) se[i] = sorted_se[e + i];
    ushort4 u[8];
#pragma unroll
    for (int i = 0; i < 8; ++i)
      u[i] = *(const ushort4*)(h_bf + (size_t)se[i].x * EMB + sub * 4);
#pragma unroll
    for (int i = 0; i < 8; ++i) {
      float4 w = combo[se[i].y];
      float4 vf = {bf2f(u[i].x), bf2f(u[i].y), bf2f(u[i].z), bf2f(u[i].w)};
      a0 += vf * w.x;
      a1 += vf * w.y;
      a2 += vf * w.z;
    }
  }
  if (e < end) {                           // tail chunk: clamped + weight-selected
    int2 se[8];
#pragma unroll
    for (int i = 0; i < 8; ++i) {
      int idx = e + i;
      se[i] = sorted_se[idx < end ? idx : end - 1];
    }
    ushort4 u[8];
#pragma unroll
    for (int i = 0; i < 8; ++i)
      u[i] = *(const ushort4*)(h_bf + (size_t)se[i].x * EMB + sub * 4);
#pragma unroll
    for (int i = 0; i < 8; ++i) {
      float4 w = (e + i < end) ? combo[se[i].y] : float4{0.f, 0.f, 0.f, 0.f};
      float4 vf = {bf2f(u[i].x), bf2f(u[i].y), bf2f(u[i].z), bf2f(u[i].w)};
      a0 += vf * w.x;
      a1 += vf * w.y;
      a2 += vf * w.z;
    }
  }
  size_t base = (size_t)node * TDIM + sub * 4;
  *(ushort4*)(t_bf + base)       = ushort4{f2bf(a0.x), f2bf(a0.y), f2bf(a0.z), f2bf(a0.w)};
  *(ushort4*)(t_bf + base + 128) = ushort4{f2bf(a1.x), f2bf(a1.y), f2bf(a1.z), f2bf(a1.w)};
  *(ushort4*)(t_bf + base + 256) = ushort4{f2bf(a2.x), f2bf(a2.y), f2bf(a2.z), f2bf(a2.w)};
}

// ---------------- MFMA GEMM: stage 32 t-rows into LDS, per-wave GEMM, bf16 residual ----------------
// Block 512 thr = 8 waves; 32 nodes/block; grid 1563. Wave wv owns cols wv*16..+15:
// 12 resident B-frags, 2 row-tiles (A via ds_read_b128), 12 chained MFMAs each.
// Epilogue: bias+relu + bf16 residual. h ping-pong (gather safety).
// A-frag: A[m=lane&15][k=(lane>>4)*8+j]; B-frag: B[k][n=lane&15];
// C/D: col=lane&15, row=(lane>>4)*4+reg.
__global__ __launch_bounds__(512) void k_gemm(const unsigned short* __restrict__ t_bf,
                                              const unsigned short* __restrict__ wt,  // [128][384]
                                              const float* __restrict__ bl,  // [3][128]
                                              const unsigned short* __restrict__ h_in_bf,
                                              unsigned short* __restrict__ h_out_bf,
                                              int do_relu) {
  __shared__ unsigned short ts[32 * TS_LD];   // 24.5 KB
  const int nb = blockIdx.x * 32;
  for (int i = threadIdx.x; i < 32 * 48; i += 512) {
    int r = i / 48, cc = i % 48;
    bf16x8 v = {};
    int row = nb + r;
    if (row < N_NODES) v = *(const bf16x8*)(t_bf + (size_t)row * TDIM + cc * 8);
    *(bf16x8*)(ts + r * TS_LD + cc * 8) = v;
  }
  __syncthreads();

  const int wv = threadIdx.x >> 6;
  const int lane = threadIdx.x & 63;
  const int m = lane & 15;
  const int kq = lane >> 4;
  const int c = wv * 16 + m;

  const unsigned short* pB = wt + (size_t)c * TDIM + kq * 8;
  bf16x8 B[12];
#pragma unroll
  for (int kc = 0; kc < 12; ++kc) B[kc] = *(const bf16x8*)(pB + kc * 32);

  const float bias = bl[c] + bl[128 + c] + bl[256 + c];

#pragma unroll
  for (int rt = 0; rt < 2; ++rt) {
    const unsigned short* pA = ts + (rt * 16 + m) * TS_LD + kq * 8;
    bf16x8 A[12];
#pragma unroll
    for (int kc = 0; kc < 12; ++kc) A[kc] = *(const bf16x8*)(pA + kc * 32);
    f32x4 acc = {0.f, 0.f, 0.f, 0.f};
#pragma unroll
    for (int kc = 0; kc < 12; ++kc) acc = MFMA_BF16(A[kc], B[kc], acc);
#pragma unroll
    for (int r = 0; r < 4; ++r) {
      int row = nb + rt * 16 + kq * 4 + r;
      if (row < N_NODES) {
        size_t idx = (size_t)row * EMB + c;
        float v = acc[r] + bias;
        if (do_relu) v = fmaxf(v, 0.f);
        float hn = bf2f(h_in_bf[idx]) + v;
        h_out_bf[idx] = f2bf(hn);
      }
    }
  }
}

// ---------------- fused mean-pool + head: block g reduces its contiguous node range ----------------
__global__ __launch_bounds__(128) void k_head(const unsigned short* __restrict__ h_bf,
                                              const int* __restrict__ gs,
                                              const float* __restrict__ fc1_w,
                                              const float* __restrict__ fc1_b,
                                              const float* __restrict__ fc2_w,
                                              const float* __restrict__ fc2_b,
                                              float* __restrict__ out) {
  __shared__ float hg[EMB];
  __shared__ float red[EMB];
  int g = blockIdx.x, e = threadIdx.x;
  int ns = gs[g], ne = gs[g + 1];
  float acc = 0.f;
  for (int n = ns; n < ne; ++n) acc += bf2f(h_bf[(size_t)n * EMB + e]);
  float cnt = fmaxf((float)(ne - ns), 1.f);
  hg[e] = acc / cnt;
  __syncthreads();
  float a2 = fc1_b[e];
  for (int j = 0; j < EMB; ++j) a2 += hg[j] * fc1_w[j * EMB + e];
  red[e] = a2 * fc2_w[e];
  __syncthreads();
  for (int s = 64; s > 0; s >>= 1) {
    if (e < s) red[e] += red[e + s];
    __syncthreads();
  }
  if (e == 0) out[g] = red[0] + fc2_b[0];
}

extern "C" void kernel_launch(void* const* d_in, const int* in_sizes, int n_in,
                              void* d_out, int out_size, void* d_ws, size_t ws_size,
                              hipStream_t stream) {
  const int*   x        = (const int*)d_in[0];
  const int*   ei       = (const int*)d_in[1];
  const int*   ea       = (const int*)d_in[2];
  const int*   batch    = (const int*)d_in[3];
  const float* atom_emb = (const float*)d_in[4];
  const float* bond_emb = (const float*)d_in[5];
  const float* W        = (const float*)d_in[6];
  const float* b        = (const float*)d_in[7];
  const float* fc1_w    = (const float*)d_in[8];
  const float* fc1_b    = (const float*)d_in[9];
  const float* fc2_w    = (const float*)d_in[10];
  const float* fc2_b    = (const float*)d_in[11];
  float* out = (float*)d_out;

  char* p = (char*)d_ws;
  auto alloc = [&](size_t bytes) { char* r = p; p += (bytes + 255) & ~(size_t)255; return r; };
  unsigned short* h0_bf      = (unsigned short*)alloc((size_t)HN * 2);
  unsigned short* h1_bf      = (unsigned short*)alloc((size_t)HN * 2);
  unsigned short* t_bf       = (unsigned short*)alloc((size_t)N_NODES * TDIM * 2);
  unsigned short* wt         = (unsigned short*)alloc((size_t)3 * 128 * TDIM * 2);
  int*            gs         = (int*)alloc((size_t)(N_GRAPHS + 1) * 4);
  int*            deg        = (int*)alloc((size_t)N_NODES * 4);
  int*            row_start  = (int*)alloc((size_t)(N_NODES + 1) * 4);
  int*            cursor     = (int*)alloc((size_t)N_NODES * 4);
  int*            partials   = (int*)alloc(256 * 4);
  int2*           sorted_se  = (int2*)alloc((size_t)(N_EDGES + 8) * 8);

  hipMemsetAsync(deg, 0, N_NODES * sizeof(int), stream);
  const int pre_blocks = PRE_ATOM_NB + PRE_HIST_NB + PRE_WCONV_NB + PRE_GB_NB;
  k_pre<<<pre_blocks, 384, 0, stream>>>(x, atom_emb, h0_bf, ei, deg, W, wt, batch, gs);
  k_scan_a<<<SCAN_NB, 256, 0, stream>>>(deg, row_start, partials);
  k_scan_b<<<1, 256, 0, stream>>>(partials, row_start);
  k_scan_c<<<SCAN_NB, 256, 0, stream>>>(row_start, partials, cursor);
  k_scatter<<<(N_EDGES + 255) / 256, 256, 0, stream>>>(ei, ea, cursor, sorted_se);

  unsigned short* hib = h0_bf;
  unsigned short* hob = h1_bf;
  const int gemm_blocks = (N_NODES + 31) / 32;  // 1563
  for (int layer = 0; layer < 3; ++layer) {
    k_agg<<<N_NODES / 8, 256, 0, stream>>>(sorted_se, row_start, bond_emb + layer * 72,
                                           hib, t_bf);
    k_gemm<<<gemm_blocks, 512, 0, stream>>>(
        t_bf, wt + (size_t)layer * 128 * TDIM, b + layer * 3 * EMB,
        hib, hob, layer < 2 ? 1 : 0);
    unsigned short* tb = hib; hib = hob; hob = tb;
  }
  // final h is in hib (h1_bf after 3 swaps)

  k_head<<<N_GRAPHS, 128, 0, stream>>>(hib, gs, fc1_w, fc1_b, fc2_w, fc2_b, out);
}